// Round 4
// baseline (666.703 us; speedup 1.0000x reference)
//
#include <hip/hip_runtime.h>
#include <hip/hip_bf16.h>

// Problem constants (from reference): B=8, N=1024, T=64, C=16, OC=16, E=16384
#define BB  8
#define NN  1024
#define TT  64
#define CC  16
#define OCC 16
#define EE  16384
#define CHO 80   // output channels: 4*OC temporal + OC spatial

// ---------------- graph preprocessing ----------------

__global__ void k_zero(int* p, int n) {
    int i = blockIdx.x * 256 + threadIdx.x;
    if (i < n) p[i] = 0;
}

__global__ void k_count(const int* __restrict__ ei, int* __restrict__ cnt) {
    int e = blockIdx.x * 256 + threadIdx.x;
    if (e < EE) atomicAdd(&cnt[ei[EE + e]], 1);   // col = ei[1][e]
}

__global__ __launch_bounds__(1024) void k_scan(const int* __restrict__ cnt,
                                               int* __restrict__ off,
                                               float* __restrict__ dinv) {
    __shared__ int s[NN];
    int n = threadIdx.x;
    int v = cnt[n];
    s[n] = v;
    __syncthreads();
    for (int d = 1; d < NN; d <<= 1) {
        int add = (n >= d) ? s[n - d] : 0;
        __syncthreads();
        s[n] += add;
        __syncthreads();
    }
    off[n]  = s[n] - v;                      // exclusive prefix
    dinv[n] = rsqrtf((float)v + 1.0f);       // deg = indeg + 1 (self loop)
}

__global__ void k_fill(const int* __restrict__ ei, const int* __restrict__ off,
                       const float* __restrict__ dinv, int* __restrict__ cursor,
                       int* __restrict__ src, float* __restrict__ wE) {
    int e = blockIdx.x * 256 + threadIdx.x;
    if (e >= EE) return;
    int r = ei[e], c = ei[EE + e];
    int p = atomicAdd(&cursor[c], 1);
    int i = off[c] + p;
    src[i] = r;
    wE[i]  = dinv[r] * dinv[c];
}

// ---------------- temporal multi-scale conv branches -> out[..., 0:64] ----------------

__global__ __launch_bounds__(256) void k_tconv(
    const float* __restrict__ x,
    const float* __restrict__ w2,  const float* __restrict__ b2,
    const float* __restrict__ w3,  const float* __restrict__ b3,
    const float* __restrict__ w6,  const float* __restrict__ b6,
    const float* __restrict__ w12, const float* __restrict__ b12,
    float* __restrict__ out) {
    __shared__ float xs[TT * CC];      // [t][c]
    __shared__ float wl[5888];         // per-branch transposed [k][c][oc]; bases 0,512,1280,2816
    __shared__ float bl[4 * OCC];
    int tid = threadIdx.x;
    size_t bn = blockIdx.x;            // b*N + n

    // stage x tile (contiguous 1024 f32 = 256 float4)
    const float4* xp = (const float4*)(x + bn * (TT * CC));
    {
        float4 u = xp[tid];
        xs[4 * tid]     = u.x;
        xs[4 * tid + 1] = u.y;
        xs[4 * tid + 2] = u.z;
        xs[4 * tid + 3] = u.w;
    }

    const float* wsrc[4] = {w2, w3, w6, w12};
    const float* bsrc[4] = {b2, b3, b6, b12};
    const int ksA[4]   = {2, 3, 6, 12};
    const int baseA[4] = {0, 512, 1280, 2816};
#pragma unroll
    for (int br = 0; br < 4; br++) {
        int ks = ksA[br], nel = OCC * CC * ks, base = baseA[br];
        for (int e = tid; e < nel; e += 256) {
            int oc = e / (CC * ks);
            int rem = e - oc * (CC * ks);
            int c = rem / ks, k = rem - c * ks;
            wl[base + (k * CC + c) * OCC + oc] = wsrc[br][e];
        }
        if (tid < OCC) bl[br * OCC + tid] = bsrc[br][tid];
    }
    __syncthreads();

    int oc = tid & 15, tq = tid >> 4;
    const int plA[4] = {0, 1, 2, 6};
    for (int i = 0; i < 4; i++) {
        int t = tq + i * 16;
        size_t orow = (bn * TT + t) * CHO;
#pragma unroll
        for (int br = 0; br < 4; br++) {
            int ks = ksA[br], l = plA[br], base = baseA[br];
            float a = bl[br * OCC + oc];
            for (int k = 0; k < ks; k++) {
                int ti = t + k - l;
                ti = ti < 0 ? 0 : (ti > TT - 1 ? TT - 1 : ti);   // replication pad
                const float* xr = xs + ti * CC;
                const float* wr = wl + base + k * CC * OCC + oc;
#pragma unroll
                for (int c = 0; c < CC; c++) a += wr[c * OCC] * xr[c];
            }
            out[orow + br * OCC + oc] = tanhf(a);
        }
    }
}

// ---------------- GCN: aggregate raw x (CSR gather), transform by W, slin, tanh ----------------
// Uses linearity: agg_o = (d2*x_n + sum_j wE_j * x_src_j) @ W + b_gcn. No xl materialization.

__global__ __launch_bounds__(256) void k_gcn(
    const float* __restrict__ x, const int* __restrict__ off, const int* __restrict__ cnt,
    const int* __restrict__ src, const float* __restrict__ wE, const float* __restrict__ dinv,
    const float* __restrict__ wg, const float* __restrict__ bg,
    const float* __restrict__ wsl, const float* __restrict__ bsl,
    float* __restrict__ out) {
    __shared__ float axs[TT * CC];     // aggregated x  [t][c]
    __shared__ float xlA[TT * OCC];    // transformed   [t][o]
    __shared__ float wl[TT * 65];      // w_slin [s][t], padded to 65
    __shared__ float wgs[OCC * CC];    // w_gcn transposed [c][o]
    __shared__ float blg[OCC];
    __shared__ float bls[TT];
    int tid = threadIdx.x;
    int b = blockIdx.x >> 10, n = blockIdx.x & (NN - 1);

    // stage w_slin [s][t]  (64x64 f32 = 1024 float4)
    const float4* wp = (const float4*)wsl;
    for (int e = tid; e < TT * TT / 4; e += 256) {
        int idx = 4 * e;
        int s = idx >> 6, t = idx & 63;
        float4 u = wp[e];
        wl[s * 65 + t]     = u.x;
        wl[s * 65 + t + 1] = u.y;
        wl[s * 65 + t + 2] = u.z;
        wl[s * 65 + t + 3] = u.w;
    }
    // stage w_gcn transposed: wg flat [o][c] -> wgs[c][o]
    {
        int o = tid >> 4, c = tid & 15;
        wgs[c * OCC + o] = wg[tid];
    }
    if (tid < OCC) blg[tid] = bg[tid];
    if (tid < TT)  bls[tid] = bsl[tid];

    // ---- aggregate neighbors (each thread owns 4 consecutive (t,c) slots via float4) ----
    int o0 = off[n], cn = cnt[n];
    float d = dinv[n], d2 = d * d;
    const float4* xn4 = (const float4*)(x + (size_t)(b * NN + n) * (TT * CC));
    float4 acc = xn4[tid];
    acc.x *= d2; acc.y *= d2; acc.z *= d2; acc.w *= d2;
    for (int j = 0; j < cn; j++) {
        int s = src[o0 + j];
        float w = wE[o0 + j];
        const float4* xs4 = (const float4*)(x + (size_t)(b * NN + s) * (TT * CC));
        float4 v = xs4[tid];
        acc.x += w * v.x; acc.y += w * v.y; acc.z += w * v.z; acc.w += w * v.w;
    }
    ((float4*)axs)[tid] = acc;
    __syncthreads();

    // ---- transform by w_gcn + bias ----
    int o = tid & 15, tq = tid >> 4;
#pragma unroll
    for (int i = 0; i < 4; i++) {
        int t = tq + i * 16;
        float a = blg[o];
        const float* ar = axs + t * CC;
#pragma unroll
        for (int c = 0; c < CC; c++) a += wgs[c * OCC + o] * ar[c];
        xlA[t * OCC + o] = a;
    }
    __syncthreads();

    // ---- slin over t + tanh + store ----
    for (int i = 0; i < 4; i++) {
        int s = tq + i * 16;
        float a = bls[s];
        const float* wr = wl + s * 65;
#pragma unroll
        for (int t = 0; t < TT; t++) a += wr[t] * xlA[t * OCC + o];
        out[((size_t)(b * NN + n) * TT + s) * CHO + 64 + o] = tanhf(a);
    }
}

// ---------------- launch ----------------

extern "C" void kernel_launch(void* const* d_in, const int* in_sizes, int n_in,
                              void* d_out, int out_size, void* d_ws, size_t ws_size,
                              hipStream_t stream) {
    const float* x   = (const float*)d_in[0];
    const int*   ei  = (const int*)d_in[1];
    const float* w2  = (const float*)d_in[2];
    const float* b2  = (const float*)d_in[3];
    const float* w3  = (const float*)d_in[4];
    const float* b3  = (const float*)d_in[5];
    const float* w6  = (const float*)d_in[6];
    const float* b6  = (const float*)d_in[7];
    const float* w12 = (const float*)d_in[8];
    const float* b12 = (const float*)d_in[9];
    const float* wg  = (const float*)d_in[10];
    const float* bg  = (const float*)d_in[11];
    const float* wsl = (const float*)d_in[12];
    const float* bsl = (const float*)d_in[13];
    float* out = (float*)d_out;

    // ws layout (bytes): cnt[N] | cursor[N] | off[N] | dinv[N] | src[E] | wE[E]  = 147456 B total
    char*  ws     = (char*)d_ws;
    int*   cnt    = (int*)(ws);
    int*   cursor = (int*)(ws + 4096);
    int*   off    = (int*)(ws + 8192);
    float* dinv   = (float*)(ws + 12288);
    int*   src    = (int*)(ws + 16384);
    float* wE     = (float*)(ws + 81920);

    k_zero<<<8, 256, 0, stream>>>(cnt, 2048);                 // zero cnt + cursor (contiguous)
    k_count<<<EE / 256, 256, 0, stream>>>(ei, cnt);
    k_scan<<<1, 1024, 0, stream>>>(cnt, off, dinv);
    k_fill<<<EE / 256, 256, 0, stream>>>(ei, off, dinv, cursor, src, wE);
    k_tconv<<<BB * NN, 256, 0, stream>>>(x, w2, b2, w3, b3, w6, b6, w12, b12, out);
    k_gcn<<<BB * NN, 256, 0, stream>>>(x, off, cnt, src, wE, dinv, wg, bg, wsl, bsl, out);
}

// Round 5
// 216.430 us; speedup vs baseline: 3.0805x; 3.0805x over previous
//
#include <hip/hip_runtime.h>
#include <hip/hip_bf16.h>

// Problem constants (from reference): B=8, N=1024, T=64, C=16, OC=16, E=16384
#define BB  8
#define NN  1024
#define TT  64
#define CC  16
#define OCC 16
#define EE  16384
#define CHO 80   // output channels: 4*OC temporal + OC spatial

// ---------------- graph preprocessing ----------------

__global__ void k_zero(int* p, int n) {
    int i = blockIdx.x * 256 + threadIdx.x;
    if (i < n) p[i] = 0;
}

__global__ void k_count(const int* __restrict__ ei, int* __restrict__ cnt) {
    int e = blockIdx.x * 256 + threadIdx.x;
    if (e < EE) atomicAdd(&cnt[ei[EE + e]], 1);   // col = ei[1][e]
}

__global__ __launch_bounds__(1024) void k_scan(const int* __restrict__ cnt,
                                               int* __restrict__ off,
                                               float* __restrict__ dinv) {
    __shared__ int s[NN];
    int n = threadIdx.x;
    int v = cnt[n];
    s[n] = v;
    __syncthreads();
    for (int d = 1; d < NN; d <<= 1) {
        int add = (n >= d) ? s[n - d] : 0;
        __syncthreads();
        s[n] += add;
        __syncthreads();
    }
    off[n]  = s[n] - v;                      // exclusive prefix
    dinv[n] = rsqrtf((float)v + 1.0f);       // deg = indeg + 1 (self loop)
}

__global__ void k_fill(const int* __restrict__ ei, const int* __restrict__ off,
                       const float* __restrict__ dinv, int* __restrict__ cursor,
                       int* __restrict__ src, float* __restrict__ wE) {
    int e = blockIdx.x * 256 + threadIdx.x;
    if (e >= EE) return;
    int r = ei[e], c = ei[EE + e];
    int p = atomicAdd(&cursor[c], 1);
    int i = off[c] + p;
    src[i] = r;
    wE[i]  = dinv[r] * dinv[c];
}

// ---------------- weight transpose: wT[br][k][c][oc] + biases at tail ----------------
// bases (floats): br0(ks2)=0, br1(ks3)=512, br2(ks6)=1280, br3(ks12)=2816; biases at 5888..5951

__global__ void k_wt(const float* __restrict__ w2,  const float* __restrict__ b2,
                     const float* __restrict__ w3,  const float* __restrict__ b3,
                     const float* __restrict__ w6,  const float* __restrict__ b6,
                     const float* __restrict__ w12, const float* __restrict__ b12,
                     float* __restrict__ wT) {
    int e = blockIdx.x * 256 + threadIdx.x;
    if (e >= 5952) return;
    const float* wsrc[4] = {w2, w3, w6, w12};
    const float* bsrc[4] = {b2, b3, b6, b12};
    const int ksA[4] = {2, 3, 6, 12};
    const int baseA[4] = {0, 512, 1280, 2816};
    if (e >= 5888) {                       // biases
        int i = e - 5888;
        wT[e] = bsrc[i >> 4][i & 15];
        return;
    }
    int br = (e < 512) ? 0 : (e < 1280) ? 1 : (e < 2816) ? 2 : 3;
    int rem = e - baseA[br];
    int k = rem >> 8, c = (rem >> 4) & 15, oc = rem & 15;
    wT[e] = wsrc[br][oc * (CC * ksA[br]) + c * ksA[br] + k];
}

// ---------------- temporal multi-scale conv -> out[..., 0:64] ----------------
// wave = branch, lane = t. Weights via wave-uniform s_load (SGPR), x via swizzled LDS.
// Per (k,c): 1 ds_read_b32 feeds 16 v_fma (acc over all oc) -> VALU-bound.

__global__ __launch_bounds__(256) void k_tconv(
    const float* __restrict__ x, const float* __restrict__ wT,
    float* __restrict__ out) {
    __shared__ float xs[TT * CC];   // swizzled: word = ti*16 + ((c + (ti>>1)) & 15)
    int tid = threadIdx.x;
    size_t bn = blockIdx.x;         // b*N + n

    // stage x tile with swizzle (1024 f32, one float4 per thread)
    {
        const float4* xp = (const float4*)(x + bn * (TT * CC));
        float4 u = xp[tid];
        int ti = tid >> 2, c0 = (tid & 3) * 4;
        int sh = (ti >> 1) & 15;
        float v[4] = {u.x, u.y, u.z, u.w};
#pragma unroll
        for (int q = 0; q < 4; q++) xs[ti * 16 + ((c0 + q + sh) & 15)] = v[q];
    }
    __syncthreads();

    int wave = tid >> 6, lane = tid & 63;   // lane == t
    const int ksA[4] = {2, 3, 6, 12};
    const int plA[4] = {0, 1, 2, 6};
    const int baseA[4] = {0, 512, 1280, 2816};
    int ks = ksA[wave], l = plA[wave];
    const float* wb = wT + __builtin_amdgcn_readfirstlane(baseA[wave]);
    const float* bb = wT + 5888 + __builtin_amdgcn_readfirstlane(wave * 16);

    float acc[16];
#pragma unroll
    for (int j = 0; j < 16; j++) acc[j] = bb[j];

    for (int k = 0; k < ks; k++) {
        int ti = lane + k - l;
        ti = ti < 0 ? 0 : (ti > TT - 1 ? TT - 1 : ti);   // replication pad
        int base = ti * 16, sh = (ti >> 1) & 15;
        const float* wk = wb + k * 256;
#pragma unroll
        for (int c = 0; c < 16; c++) {
            float xv = xs[base + ((c + sh) & 15)];
#pragma unroll
            for (int j = 0; j < 16; j++) acc[j] = fmaf(wk[c * 16 + j], xv, acc[j]);
        }
    }

    // tanh + store 16 oc as 4 float4
    float* op = out + (bn * TT + lane) * CHO + wave * 16;
#pragma unroll
    for (int q = 0; q < 4; q++) {
        float4 o;
        o.x = tanhf(acc[4 * q]);
        o.y = tanhf(acc[4 * q + 1]);
        o.z = tanhf(acc[4 * q + 2]);
        o.w = tanhf(acc[4 * q + 3]);
        ((float4*)op)[q] = o;
    }
}

// ---------------- GCN: aggregate raw x (CSR gather), transform by W, slin, tanh ----------------
// Uses linearity: agg_o = (d2*x_n + sum_j wE_j * x_src_j) @ W + b_gcn. No xl materialization.

__global__ __launch_bounds__(256) void k_gcn(
    const float* __restrict__ x, const int* __restrict__ off, const int* __restrict__ cnt,
    const int* __restrict__ src, const float* __restrict__ wE, const float* __restrict__ dinv,
    const float* __restrict__ wg, const float* __restrict__ bg,
    const float* __restrict__ wsl, const float* __restrict__ bsl,
    float* __restrict__ out) {
    __shared__ float axs[TT * CC];     // aggregated x  [t][c]
    __shared__ float xlA[TT * OCC];    // transformed   [t][o]
    __shared__ float wl[TT * 65];      // w_slin [s][t], padded to 65
    __shared__ float wgs[OCC * CC];    // w_gcn transposed [c][o]
    __shared__ float blg[OCC];
    __shared__ float bls[TT];
    int tid = threadIdx.x;
    int b = blockIdx.x >> 10, n = blockIdx.x & (NN - 1);

    // stage w_slin [s][t]  (64x64 f32 = 1024 float4)
    const float4* wp = (const float4*)wsl;
    for (int e = tid; e < TT * TT / 4; e += 256) {
        int idx = 4 * e;
        int s = idx >> 6, t = idx & 63;
        float4 u = wp[e];
        wl[s * 65 + t]     = u.x;
        wl[s * 65 + t + 1] = u.y;
        wl[s * 65 + t + 2] = u.z;
        wl[s * 65 + t + 3] = u.w;
    }
    // stage w_gcn transposed: wg flat [o][c] -> wgs[c][o]
    {
        int o = tid >> 4, c = tid & 15;
        wgs[c * OCC + o] = wg[tid];
    }
    if (tid < OCC) blg[tid] = bg[tid];
    if (tid < TT)  bls[tid] = bsl[tid];

    // ---- aggregate neighbors (each thread owns 4 consecutive (t,c) slots via float4) ----
    int o0 = off[n], cn = cnt[n];
    float d = dinv[n], d2 = d * d;
    const float4* xn4 = (const float4*)(x + (size_t)(b * NN + n) * (TT * CC));
    float4 acc = xn4[tid];
    acc.x *= d2; acc.y *= d2; acc.z *= d2; acc.w *= d2;
    for (int j = 0; j < cn; j++) {
        int s = src[o0 + j];
        float w = wE[o0 + j];
        const float4* xs4 = (const float4*)(x + (size_t)(b * NN + s) * (TT * CC));
        float4 v = xs4[tid];
        acc.x += w * v.x; acc.y += w * v.y; acc.z += w * v.z; acc.w += w * v.w;
    }
    ((float4*)axs)[tid] = acc;
    __syncthreads();

    // ---- transform by w_gcn + bias ----
    int o = tid & 15, tq = tid >> 4;
#pragma unroll
    for (int i = 0; i < 4; i++) {
        int t = tq + i * 16;
        float a = blg[o];
        const float* ar = axs + t * CC;
#pragma unroll
        for (int c = 0; c < CC; c++) a += wgs[c * OCC + o] * ar[c];
        xlA[t * OCC + o] = a;
    }
    __syncthreads();

    // ---- slin over t + tanh + store ----
    for (int i = 0; i < 4; i++) {
        int s = tq + i * 16;
        float a = bls[s];
        const float* wr = wl + s * 65;
#pragma unroll
        for (int t = 0; t < TT; t++) a += wr[t] * xlA[t * OCC + o];
        out[((size_t)(b * NN + n) * TT + s) * CHO + 64 + o] = tanhf(a);
    }
}

// ---------------- launch ----------------

extern "C" void kernel_launch(void* const* d_in, const int* in_sizes, int n_in,
                              void* d_out, int out_size, void* d_ws, size_t ws_size,
                              hipStream_t stream) {
    const float* x   = (const float*)d_in[0];
    const int*   ei  = (const int*)d_in[1];
    const float* w2  = (const float*)d_in[2];
    const float* b2  = (const float*)d_in[3];
    const float* w3  = (const float*)d_in[4];
    const float* b3  = (const float*)d_in[5];
    const float* w6  = (const float*)d_in[6];
    const float* b6  = (const float*)d_in[7];
    const float* w12 = (const float*)d_in[8];
    const float* b12 = (const float*)d_in[9];
    const float* wg  = (const float*)d_in[10];
    const float* bg  = (const float*)d_in[11];
    const float* wsl = (const float*)d_in[12];
    const float* bsl = (const float*)d_in[13];
    float* out = (float*)d_out;

    // ws layout (bytes): cnt[N] | cursor[N] | off[N] | dinv[N] | src[E] | wE[E] | wT[5952]
    char*  ws     = (char*)d_ws;
    int*   cnt    = (int*)(ws);
    int*   cursor = (int*)(ws + 4096);
    int*   off    = (int*)(ws + 8192);
    float* dinv   = (float*)(ws + 12288);
    int*   src    = (int*)(ws + 16384);
    float* wE     = (float*)(ws + 81920);
    float* wT     = (float*)(ws + 147456);

    k_zero<<<8, 256, 0, stream>>>(cnt, 2048);                 // zero cnt + cursor (contiguous)
    k_count<<<EE / 256, 256, 0, stream>>>(ei, cnt);
    k_scan<<<1, 1024, 0, stream>>>(cnt, off, dinv);
    k_fill<<<EE / 256, 256, 0, stream>>>(ei, off, dinv, cursor, src, wE);
    k_wt<<<24, 256, 0, stream>>>(w2, b2, w3, b3, w6, b6, w12, b12, wT);
    k_tconv<<<BB * NN, 256, 0, stream>>>(x, wT, out);
    k_gcn<<<BB * NN, 256, 0, stream>>>(x, off, cnt, src, wE, dinv, wg, bg, wsl, bsl, out);
}

// Round 6
// 163.297 us; speedup vs baseline: 4.0828x; 1.3254x over previous
//
#include <hip/hip_runtime.h>
#include <hip/hip_bf16.h>

// Problem constants (from reference): B=8, N=1024, T=64, C=16, OC=16, E=16384
#define BB  8
#define NN  1024
#define TT  64
#define CC  16
#define OCC 16
#define EE  16384
#define CHO 80   // output channels: 4*OC temporal + OC spatial

// fast tanh: tanh(v) = 1 - 2/(e^{2v}+1). __expf -> v_exp_f32; rcp -> v_rcp_f32.
// inf-safe: v>>0 -> e=inf -> rcp=0 -> 1; v<<0 -> e=0 -> rcp(1)=1 -> -1.
static __device__ __forceinline__ float tanh_fast(float v) {
    float e = __expf(2.0f * v);
    return 1.0f - 2.0f * __builtin_amdgcn_rcpf(e + 1.0f);
}

// ---------------- graph preprocessing ----------------

__global__ void k_zero(int* p, int n) {
    int i = blockIdx.x * 256 + threadIdx.x;
    if (i < n) p[i] = 0;
}

__global__ void k_count(const int* __restrict__ ei, int* __restrict__ cnt) {
    int e = blockIdx.x * 256 + threadIdx.x;
    if (e < EE) atomicAdd(&cnt[ei[EE + e]], 1);   // col = ei[1][e]
}

__global__ __launch_bounds__(1024) void k_scan(const int* __restrict__ cnt,
                                               int* __restrict__ off,
                                               float* __restrict__ dinv) {
    __shared__ int s[NN];
    int n = threadIdx.x;
    int v = cnt[n];
    s[n] = v;
    __syncthreads();
    for (int d = 1; d < NN; d <<= 1) {
        int add = (n >= d) ? s[n - d] : 0;
        __syncthreads();
        s[n] += add;
        __syncthreads();
    }
    off[n]  = s[n] - v;                      // exclusive prefix
    dinv[n] = rsqrtf((float)v + 1.0f);       // deg = indeg + 1 (self loop)
}

__global__ void k_fill(const int* __restrict__ ei, const int* __restrict__ off,
                       const float* __restrict__ dinv, int* __restrict__ cursor,
                       int* __restrict__ src, float* __restrict__ wE) {
    int e = blockIdx.x * 256 + threadIdx.x;
    if (e >= EE) return;
    int r = ei[e], c = ei[EE + e];
    int p = atomicAdd(&cursor[c], 1);
    int i = off[c] + p;
    src[i] = r;
    wE[i]  = dinv[r] * dinv[c];
}

// ---------------- weight transpose ----------------
// wT floats: [0..5888) conv wT[br][k][c][oc]; [5888..5952) conv biases;
//            [5952..6208) wgT[c][o]; [6208..6224) bg.

__global__ void k_wt(const float* __restrict__ w2,  const float* __restrict__ b2,
                     const float* __restrict__ w3,  const float* __restrict__ b3,
                     const float* __restrict__ w6,  const float* __restrict__ b6,
                     const float* __restrict__ w12, const float* __restrict__ b12,
                     const float* __restrict__ wg,  const float* __restrict__ bg,
                     float* __restrict__ wT) {
    int e = blockIdx.x * 256 + threadIdx.x;
    if (e >= 6224) return;
    const float* wsrc[4] = {w2, w3, w6, w12};
    const float* bsrc[4] = {b2, b3, b6, b12};
    const int ksA[4] = {2, 3, 6, 12};
    const int baseA[4] = {0, 512, 1280, 2816};
    if (e >= 6208) { wT[e] = bg[e - 6208]; return; }
    if (e >= 5952) {                       // wgT[c][o] = wg[o][c]
        int i = e - 5952, c = i >> 4, o = i & 15;
        wT[e] = wg[o * CC + c];
        return;
    }
    if (e >= 5888) {                       // conv biases
        int i = e - 5888;
        wT[e] = bsrc[i >> 4][i & 15];
        return;
    }
    int br = (e < 512) ? 0 : (e < 1280) ? 1 : (e < 2816) ? 2 : 3;
    int rem = e - baseA[br];
    int k = rem >> 8, c = (rem >> 4) & 15, oc = rem & 15;
    wT[e] = wsrc[br][oc * (CC * ksA[br]) + c * ksA[br] + k];
}

// ---------------- temporal multi-scale conv -> out[..., 0:64] ----------------
// wave role rotated per block (SIMD load balance). lane = t.
// x in LDS rows padded to 17 words: bank = (17t+c)%32, 17 coprime 32 -> 2 lanes/bank (free).
// reads use compile-time offset immediates; weights via wave-uniform s_load.

__global__ __launch_bounds__(256) void k_tconv(
    const float* __restrict__ x, const float* __restrict__ wT,
    float* __restrict__ out) {
    __shared__ float xs[TT * 17];
    int tid = threadIdx.x;
    size_t bn = blockIdx.x;         // b*N + n

    {   // stage x tile (1024 f32, one float4 per thread) into padded rows
        const float4* xp = (const float4*)(x + bn * (TT * CC));
        float4 u = xp[tid];
        float* w = xs + (tid >> 2) * 17 + (tid & 3) * 4;
        w[0] = u.x; w[1] = u.y; w[2] = u.z; w[3] = u.w;
    }
    __syncthreads();

    int wave = tid >> 6, lane = tid & 63;   // lane == t
    int role = __builtin_amdgcn_readfirstlane((wave + (int)(blockIdx.x & 3)) & 3);
    const int ksA[4] = {2, 3, 6, 12};
    const int plA[4] = {0, 1, 2, 6};
    const int baseA[4] = {0, 512, 1280, 2816};
    int ks = ksA[role], l = plA[role];
    const float* wb = wT + baseA[role];
    const float* bb = wT + 5888 + role * 16;

    float acc[16];
#pragma unroll
    for (int j = 0; j < 16; j++) acc[j] = bb[j];

    for (int k = 0; k < ks; k++) {
        int ti = lane + k - l;
        ti = ti < 0 ? 0 : (ti > TT - 1 ? TT - 1 : ti);   // replication pad (v_med3)
        const float* xr = xs + ti * 17;
        const float* wk = wb + k * 256;
#pragma unroll
        for (int c = 0; c < 16; c++) {
            float xv = xr[c];                 // ds_read_b32, imm offset
#pragma unroll
            for (int j = 0; j < 16; j++) acc[j] = fmaf(wk[c * 16 + j], xv, acc[j]);
        }
    }

    float* op = out + (bn * TT + lane) * CHO + role * 16;
#pragma unroll
    for (int q = 0; q < 4; q++) {
        float4 o;
        o.x = tanh_fast(acc[4 * q]);
        o.y = tanh_fast(acc[4 * q + 1]);
        o.z = tanh_fast(acc[4 * q + 2]);
        o.w = tanh_fast(acc[4 * q + 3]);
        ((float4*)op)[q] = o;
    }
}

// ---------------- GCN: aggregate raw x (CSR gather), transform, slin, tanh ----------------
// linearity: agg = (d2*x_n + sum_j wE_j x_src_j); xlA = agg @ Wg + bg; out = wsl @ xlA + bsl.
// wave = og (4 o-channel groups, wave-uniform -> weights from SGPRs), lane = t / s.

__global__ __launch_bounds__(256) void k_gcn(
    const float* __restrict__ x, const int* __restrict__ off, const int* __restrict__ cnt,
    const int* __restrict__ src, const float* __restrict__ wE, const float* __restrict__ dinv,
    const float* __restrict__ wT, const float* __restrict__ wsl,
    const float* __restrict__ bsl, float* __restrict__ out) {
    __shared__ float wl[TT * 65];      // w_slin [s][t], pad 65
    __shared__ float axs[TT * 17];     // aggregated x [t][c], pad 17
    __shared__ float xlA[TT * OCC];    // transformed [t][o], unpadded (b128 access)
    int tid = threadIdx.x;
    int b = blockIdx.x >> 10, n = blockIdx.x & (NN - 1);

    // stage w_slin [s][t]
    const float4* wp = (const float4*)wsl;
    for (int e = tid; e < TT * TT / 4; e += 256) {
        int idx = 4 * e;
        int s = idx >> 6, t = idx & 63;
        float4 u = wp[e];
        float* w = wl + s * 65 + t;
        w[0] = u.x; w[1] = u.y; w[2] = u.z; w[3] = u.w;
    }

    // ---- aggregate neighbors (thread owns 4 consecutive (t,c) words) ----
    int o0 = off[n], cn = cnt[n];
    float d = dinv[n], d2 = d * d;
    const float4* xn4 = (const float4*)(x + (size_t)(b * NN + n) * (TT * CC));
    float4 acc = xn4[tid];
    acc.x *= d2; acc.y *= d2; acc.z *= d2; acc.w *= d2;
    for (int j = 0; j < cn; j++) {
        int s = src[o0 + j];
        float w = wE[o0 + j];
        const float4* xs4 = (const float4*)(x + (size_t)(b * NN + s) * (TT * CC));
        float4 v = xs4[tid];
        acc.x += w * v.x; acc.y += w * v.y; acc.z += w * v.z; acc.w += w * v.w;
    }
    {
        float* w = axs + (tid >> 2) * 17 + (tid & 3) * 4;
        w[0] = acc.x; w[1] = acc.y; w[2] = acc.z; w[3] = acc.w;
    }
    __syncthreads();

    int og = __builtin_amdgcn_readfirstlane(tid >> 6);
    const float* wgT = wT + 5952;      // [c][o]
    const float* bgp = wT + 6208;

    // ---- transform: lane = t, acc over o = og*4..+3 (weights wave-uniform -> SGPR) ----
    {
        int t = tid & 63;
        float a4[4];
#pragma unroll
        for (int q = 0; q < 4; q++) a4[q] = bgp[og * 4 + q];
        const float* ar = axs + t * 17;
#pragma unroll
        for (int c = 0; c < 16; c++) {
            float xv = ar[c];              // ds_read_b32, imm offset
#pragma unroll
            for (int q = 0; q < 4; q++)
                a4[q] = fmaf(wgT[c * 16 + og * 4 + q], xv, a4[q]);
        }
        float4 o;
        o.x = a4[0]; o.y = a4[1]; o.z = a4[2]; o.w = a4[3];
        *(float4*)(xlA + t * OCC + og * 4) = o;   // aligned ds_write_b128
    }
    __syncthreads();

    // ---- slin: lane = s, acc over o = og*4..+3 ----
    {
        int s = tid & 63;
        float bv = bsl[s];
        float a4[4] = {bv, bv, bv, bv};
        const float* wr = wl + s * 65;
        const float4* xrow = (const float4*)xlA;
#pragma unroll
        for (int t = 0; t < TT; t++) {
            float4 xv = xrow[t * 4 + og];  // wave-uniform addr -> b128 broadcast
            float wv = wr[t];              // ds_read_b32, imm offset
            a4[0] = fmaf(wv, xv.x, a4[0]);
            a4[1] = fmaf(wv, xv.y, a4[1]);
            a4[2] = fmaf(wv, xv.z, a4[2]);
            a4[3] = fmaf(wv, xv.w, a4[3]);
        }
        float4 o;
        o.x = tanh_fast(a4[0]); o.y = tanh_fast(a4[1]);
        o.z = tanh_fast(a4[2]); o.w = tanh_fast(a4[3]);
        *(float4*)(out + ((size_t)(b * NN + n) * TT + s) * CHO + 64 + og * 4) = o;
    }
}

// ---------------- launch ----------------

extern "C" void kernel_launch(void* const* d_in, const int* in_sizes, int n_in,
                              void* d_out, int out_size, void* d_ws, size_t ws_size,
                              hipStream_t stream) {
    const float* x   = (const float*)d_in[0];
    const int*   ei  = (const int*)d_in[1];
    const float* w2  = (const float*)d_in[2];
    const float* b2  = (const float*)d_in[3];
    const float* w3  = (const float*)d_in[4];
    const float* b3  = (const float*)d_in[5];
    const float* w6  = (const float*)d_in[6];
    const float* b6  = (const float*)d_in[7];
    const float* w12 = (const float*)d_in[8];
    const float* b12 = (const float*)d_in[9];
    const float* wg  = (const float*)d_in[10];
    const float* bg  = (const float*)d_in[11];
    const float* wsl = (const float*)d_in[12];
    const float* bsl = (const float*)d_in[13];
    float* out = (float*)d_out;

    // ws layout (bytes): cnt[N] | cursor[N] | off[N] | dinv[N] | src[E] | wE[E] | wT[6224]
    char*  ws     = (char*)d_ws;
    int*   cnt    = (int*)(ws);
    int*   cursor = (int*)(ws + 4096);
    int*   off    = (int*)(ws + 8192);
    float* dinv   = (float*)(ws + 12288);
    int*   src    = (int*)(ws + 16384);
    float* wE     = (float*)(ws + 81920);
    float* wT     = (float*)(ws + 147456);

    k_zero<<<8, 256, 0, stream>>>(cnt, 2048);                 // zero cnt + cursor (contiguous)
    k_count<<<EE / 256, 256, 0, stream>>>(ei, cnt);
    k_scan<<<1, 1024, 0, stream>>>(cnt, off, dinv);
    k_fill<<<EE / 256, 256, 0, stream>>>(ei, off, dinv, cursor, src, wE);
    k_wt<<<25, 256, 0, stream>>>(w2, b2, w3, b3, w6, b6, w12, b12, wg, bg, wT);
    k_tconv<<<BB * NN, 256, 0, stream>>>(x, wT, out);
    k_gcn<<<BB * NN, 256, 0, stream>>>(x, off, cnt, src, wE, dinv, wT, wsl, bsl, out);
}